// Round 1
// baseline (3506.248 us; speedup 1.0000x reference)
//
#include <hip/hip_runtime.h>
#include <hip/hip_bf16.h>

#define H 768
#define NB 8
#define SLEN 2048
#define N1 1027
#define N2 517
#define N3 262
#define N4 134

__device__ __forceinline__ float sigmoidf(float v) {
    return 1.0f / (1.0f + __expf(-v));
}

// ---------------- Forward DWT (one analysis level) ----------------
// out layout: [jb][t][h], jb = j*8+b, h contiguous.
// in addressed via strides: in + j*j_stride + b*b_stride + s*t_stride + h
__global__ __launch_bounds__(256)
void dwt_analysis_kernel(const float* __restrict__ in,
                         float* __restrict__ lo,
                         float* __restrict__ hi,
                         int n_in, int n_out,
                         long j_stride, long b_stride, long t_stride)
{
    // h0r[k] = DEC_LO[7-k], h1r[k] = DEC_HI[7-k]  (lax conv = correlation, kernel pre-reversed)
    const float h0r[8] = { 0.2303778133088965f,  0.7148465705529157f,  0.6308807679298589f,
                          -0.027983769416859854f, -0.18703481171909309f, 0.030841381835560764f,
                           0.0328830116668852f, -0.010597401785069032f };
    const float h1r[8] = { -0.010597401785069032f, -0.0328830116668852f, 0.030841381835560764f,
                            0.18703481171909309f, -0.027983769416859854f, -0.6308807679298589f,
                            0.7148465705529157f, -0.2303778133088965f };
    long total = 24L * n_out * H;
    long stride = (long)gridDim.x * blockDim.x;
    for (long idx = (long)blockIdx.x * blockDim.x + threadIdx.x; idx < total; idx += stride) {
        int h = (int)(idx % H);
        long r = idx / H;
        int t = (int)(r % n_out);
        int jb = (int)(r / n_out);
        int j = jb >> 3;
        int b = jb & 7;
        const float* src = in + j * j_stride + b * b_stride + h;
        int s0 = 2 * t - 6;  // padL == 6 at every level for these sizes
        float aL = 0.f, aH = 0.f;
#pragma unroll
        for (int k = 0; k < 8; ++k) {
            int s = s0 + k;
            if (s >= 0 && s < n_in) {
                float v = src[s * t_stride];
                aL += v * h0r[k];
                aH += v * h1r[k];
            }
        }
        long o = ((long)jb * n_out + t) * H + h;
        lo[o] = aL;
        hi[o] = aH;
    }
}

// ---------------- Inverse DWT (one synthesis level) ----------------
// y[t] = sum over dilated-padded taps; pad (1,1) makes every tap a valid coeff index.
__device__ __forceinline__ float synth_val(const float* lop, const float* hip_, int t)
{
    const float g0[8] = { -0.010597401785069032f, 0.0328830116668852f, 0.030841381835560764f,
                          -0.18703481171909309f, -0.027983769416859854f, 0.6308807679298589f,
                           0.7148465705529157f, 0.2303778133088965f };
    const float g1[8] = { -0.2303778133088965f, 0.7148465705529157f, -0.6308807679298589f,
                          -0.027983769416859854f, 0.18703481171909309f, 0.030841381835560764f,
                          -0.0328830116668852f, -0.010597401785069032f };
    float acc = 0.f;
    if ((t & 1) == 0) {
        int i0 = t >> 1;
#pragma unroll
        for (int d = 0; d < 4; ++d) {
            long i = i0 + d;
            acc += lop[i * H] * g0[2 * d + 1] + hip_[i * H] * g1[2 * d + 1];
        }
    } else {
        int i0 = (t - 1) >> 1;
#pragma unroll
        for (int d = 0; d < 4; ++d) {
            long i = i0 + d;
            acc += lop[i * H] * g0[2 * d] + hip_[i * H] * g1[2 * d];
        }
    }
    return acc;
}

__global__ __launch_bounds__(256)
void dwt_synth_kernel(const float* __restrict__ lo,
                      const float* __restrict__ hi,
                      float* __restrict__ out,
                      int n, int lo_alloc, int n_out)
{
    long total = 24L * n_out * H;
    long stride = (long)gridDim.x * blockDim.x;
    for (long idx = (long)blockIdx.x * blockDim.x + threadIdx.x; idx < total; idx += stride) {
        int h = (int)(idx % H);
        long r = idx / H;
        int t = (int)(r % n_out);
        int mb = (int)(r / n_out);
        const float* lop = lo + (long)mb * lo_alloc * H + h;
        const float* hip_ = hi + (long)mb * n * H + h;
        out[((long)mb * n_out + t) * H + h] = synth_val(lop, hip_, t);
    }
}

// Final level fused with (recon - x) * weight, writing d_out [m][b][s][h]
__global__ __launch_bounds__(256)
void dwt_synth_final_kernel(const float* __restrict__ lo,
                            const float* __restrict__ hi,
                            const float* __restrict__ x,
                            const float* __restrict__ weight,
                            float* __restrict__ out,
                            int n, int lo_alloc)
{
    long total = 24L * SLEN * H;
    long stride = (long)gridDim.x * blockDim.x;
    for (long idx = (long)blockIdx.x * blockDim.x + threadIdx.x; idx < total; idx += stride) {
        int h = (int)(idx % H);
        long r = idx / H;
        int t = (int)(r % SLEN);
        int mb = (int)(r / SLEN);
        int m = mb >> 3;
        int b = mb & 7;
        const float* lop = lo + (long)mb * lo_alloc * H + h;
        const float* hip_ = hi + (long)mb * n * H + h;
        float recon = synth_val(lop, hip_, t);
        float xs = x[((long)b * SLEN + t) * (3 * H) + (long)m * H + h];
        out[((long)mb * SLEN + t) * H + h] = (recon - xs) * weight[m];
    }
}

// ---------------- Gating: fused[m,r,g] = sum_j sigmoid(coeff_j . W[m,j,g,:]) * coeff_j[r,g]
// coeff: [3][rows][H] (j-major), W addressed base + m*w_m_stride + j*w_j_stride, [g][h]
__global__ __launch_bounds__(256)
void gating_kernel(const float* __restrict__ coeff,
                   const float* __restrict__ W,
                   float* __restrict__ fused,
                   int rows, long w_m_stride, long w_j_stride)
{
    __shared__ float As[16][68];   // k-major, padded
    __shared__ float Bs[16][68];
    int m = blockIdx.z;
    int rowBase = blockIdx.x * 64;
    int colBase = blockIdx.y * 64;
    int tid = threadIdx.x;
    int tr = tid >> 4;          // 0..15 output row group
    int tc = tid & 15;          // 0..15 output col group
    int lr = tid >> 2;          // 0..63 staging row
    int lk = (tid & 3) << 2;    // 0,4,8,12 staging k

    float fus[4][4] = {{0.f}};

    for (int j = 0; j < 3; ++j) {
        const float* A = coeff + (long)j * rows * H;
        const float* Bw = W + (long)m * w_m_stride + (long)j * w_j_stride;
        float acc[4][4] = {{0.f}};

        for (int k0 = 0; k0 < H; k0 += 16) {
            int gr = rowBase + lr;
            float4 av = make_float4(0.f, 0.f, 0.f, 0.f);
            if (gr < rows) av = *(const float4*)(A + (long)gr * H + k0 + lk);
            float4 bv = *(const float4*)(Bw + (long)(colBase + lr) * H + k0 + lk);
            __syncthreads();
            As[lk + 0][lr] = av.x; As[lk + 1][lr] = av.y;
            As[lk + 2][lr] = av.z; As[lk + 3][lr] = av.w;
            Bs[lk + 0][lr] = bv.x; Bs[lk + 1][lr] = bv.y;
            Bs[lk + 2][lr] = bv.z; Bs[lk + 3][lr] = bv.w;
            __syncthreads();
#pragma unroll
            for (int kk = 0; kk < 16; ++kk) {
                float a_[4], b_[4];
                *(float4*)a_ = *(const float4*)&As[kk][tr << 2];
                *(float4*)b_ = *(const float4*)&Bs[kk][tc << 2];
#pragma unroll
                for (int ii = 0; ii < 4; ++ii)
#pragma unroll
                    for (int jj = 0; jj < 4; ++jj)
                        acc[ii][jj] += a_[ii] * b_[jj];
            }
        }
        // sigmoid-gate epilogue for this j
#pragma unroll
        for (int ii = 0; ii < 4; ++ii) {
            int r = rowBase + (tr << 2) + ii;
            if (r < rows) {
#pragma unroll
                for (int jj = 0; jj < 4; ++jj) {
                    int g = colBase + (tc << 2) + jj;
                    float c = A[(long)r * H + g];
                    fus[ii][jj] += sigmoidf(acc[ii][jj]) * c;
                }
            }
        }
    }
#pragma unroll
    for (int ii = 0; ii < 4; ++ii) {
        int r = rowBase + (tr << 2) + ii;
        if (r < rows) {
#pragma unroll
            for (int jj = 0; jj < 4; ++jj) {
                int g = colBase + (tc << 2) + jj;
                fused[((long)m * rows + r) * H + g] = fus[ii][jj];
            }
        }
    }
}

// ---------------- launch ----------------
static inline int grid_for(long total) {
    long g = (total + 255) / 256;
    if (g > 16384) g = 16384;
    return (int)g;
}

extern "C" void kernel_launch(void* const* d_in, const int* in_sizes, int n_in,
                              void* d_out, int out_size, void* d_ws, size_t ws_size,
                              hipStream_t stream)
{
    const float* x      = (const float*)d_in[0];
    const float* low_w  = (const float*)d_in[1];
    const float* high_w = (const float*)d_in[2];
    const float* weight = (const float*)d_in[3];
    float* out = (float*)d_out;
    float* ws  = (float*)d_ws;

    const long SZ1 = 24L * N1 * H;
    const long SZ2 = 24L * N2 * H;
    const long SZ3 = 24L * N3 * H;
    const long SZ4 = 24L * N4 * H;

    // Region A: forward coeffs (live through gating)
    float* A_hi1 = ws;
    float* A_hi2 = A_hi1 + SZ1;
    float* A_hi3 = A_hi2 + SZ2;
    float* A_hi4 = A_hi3 + SZ3;
    float* A_lo4 = A_hi4 + SZ4;
    // Region B: lo intermediates during forward, then fused coeffs
    float* RB    = A_lo4 + SZ4;
    float* B_lo1 = RB;
    float* B_lo2 = RB + SZ1;
    float* B_lo3 = B_lo2 + SZ2;
    float* F_hi1 = RB;                 // aliases B_lo1 (dead by gating time)
    float* F_hi2 = F_hi1 + SZ1;
    float* F_hi3 = F_hi2 + SZ2;
    float* F_hi4 = F_hi3 + SZ3;
    float* F_lo  = F_hi4 + SZ4;
    // Synthesis intermediates: alias Region A (dead after gating)
    float* Y1 = ws;                    // 24*262*H
    float* Y2 = Y1 + 24L * 262 * H;    // 24*518*H
    float* Y3 = Y2 + 24L * 518 * H;    // 24*1028*H

    // ---- forward DWT (4 levels) ----
    hipLaunchKernelGGL(dwt_analysis_kernel, dim3(grid_for(24L * N1 * H)), dim3(256), 0, stream,
                       x, B_lo1, A_hi1, SLEN, N1, 768L, (long)SLEN * 2304, 2304L);
    hipLaunchKernelGGL(dwt_analysis_kernel, dim3(grid_for(24L * N2 * H)), dim3(256), 0, stream,
                       B_lo1, B_lo2, A_hi2, N1, N2, 8L * N1 * H, (long)N1 * H, (long)H);
    hipLaunchKernelGGL(dwt_analysis_kernel, dim3(grid_for(24L * N3 * H)), dim3(256), 0, stream,
                       B_lo2, B_lo3, A_hi3, N2, N3, 8L * N2 * H, (long)N2 * H, (long)H);
    hipLaunchKernelGGL(dwt_analysis_kernel, dim3(grid_for(24L * N4 * H)), dim3(256), 0, stream,
                       B_lo3, A_lo4, A_hi4, N3, N4, 8L * N3 * H, (long)N3 * H, (long)H);

    // ---- gating (5 bands) ----
    const long HH = (long)H * H;
    {
        int rows = NB * N4;
        hipLaunchKernelGGL(gating_kernel, dim3((rows + 63) / 64, H / 64, 3), dim3(256), 0, stream,
                           A_lo4, low_w, F_lo, rows, 3L * HH, HH);
    }
    const float* hwb[4] = { high_w + 0L * 3 * HH, high_w + 1L * 3 * HH,
                            high_w + 2L * 3 * HH, high_w + 3L * 3 * HH };
    const float* ains[4] = { A_hi1, A_hi2, A_hi3, A_hi4 };
    float* fouts[4] = { F_hi1, F_hi2, F_hi3, F_hi4 };
    const int nlens[4] = { N1, N2, N3, N4 };
    for (int k = 0; k < 4; ++k) {
        int rows = NB * nlens[k];
        hipLaunchKernelGGL(gating_kernel, dim3((rows + 63) / 64, H / 64, 3), dim3(256), 0, stream,
                           ains[k], hwb[k], fouts[k], rows, 12L * HH, HH);
    }

    // ---- inverse DWT ----
    hipLaunchKernelGGL(dwt_synth_kernel, dim3(grid_for(24L * 262 * H)), dim3(256), 0, stream,
                       F_lo, F_hi4, Y1, N4, N4, 2 * N4 - 6);          // -> 262
    hipLaunchKernelGGL(dwt_synth_kernel, dim3(grid_for(24L * 518 * H)), dim3(256), 0, stream,
                       Y1, F_hi3, Y2, N3, N3, 2 * N3 - 6);            // -> 518
    hipLaunchKernelGGL(dwt_synth_kernel, dim3(grid_for(24L * 1028 * H)), dim3(256), 0, stream,
                       Y2, F_hi2, Y3, N2, 518, 2 * N2 - 6);           // n=517 (truncate 518) -> 1028
    hipLaunchKernelGGL(dwt_synth_final_kernel, dim3(grid_for(24L * SLEN * H)), dim3(256), 0, stream,
                       Y3, F_hi1, x, weight, out, N1, 1028);          // n=1027 (truncate 1028) -> 2048
}

// Round 2
// 1484.844 us; speedup vs baseline: 2.3614x; 2.3614x over previous
//
#include <hip/hip_runtime.h>
#include <hip/hip_bf16.h>

#define H 768
#define NB 8
#define SLEN 2048
#define N1 1027
#define N2 517
#define N3 262
#define N4 134

typedef short bf16x8 __attribute__((ext_vector_type(8)));
typedef float f32x4 __attribute__((ext_vector_type(4)));
typedef unsigned short ushortx8 __attribute__((ext_vector_type(8)));

__device__ __forceinline__ float sigmoidf(float v) {
    return 1.0f / (1.0f + __expf(-v));
}

__device__ __forceinline__ unsigned short f2bf(float f) {
    union { float f; unsigned u; } v; v.f = f;
    unsigned r = v.u + 0x7fffu + ((v.u >> 16) & 1u);
    return (unsigned short)(r >> 16);
}

__device__ __forceinline__ float bf2f(unsigned short u) {
    union { unsigned u; float f; } v; v.u = ((unsigned)u) << 16;
    return v.f;
}

__device__ __forceinline__ void gload_lds16(const void* g, void* l) {
    __builtin_amdgcn_global_load_lds(
        (const __attribute__((address_space(1))) unsigned int*)g,
        (__attribute__((address_space(3))) unsigned int*)l,
        16, 0, 0);
}

// ---------------- Forward DWT (one analysis level) ----------------
__global__ __launch_bounds__(256)
void dwt_analysis_kernel(const float* __restrict__ in,
                         float* __restrict__ lo,
                         float* __restrict__ hi,
                         int n_in, int n_out,
                         long j_stride, long b_stride, long t_stride)
{
    const float h0r[8] = { 0.2303778133088965f,  0.7148465705529157f,  0.6308807679298589f,
                          -0.027983769416859854f, -0.18703481171909309f, 0.030841381835560764f,
                           0.0328830116668852f, -0.010597401785069032f };
    const float h1r[8] = { -0.010597401785069032f, -0.0328830116668852f, 0.030841381835560764f,
                            0.18703481171909309f, -0.027983769416859854f, -0.6308807679298589f,
                            0.7148465705529157f, -0.2303778133088965f };
    long total = 24L * n_out * H;
    long stride = (long)gridDim.x * blockDim.x;
    for (long idx = (long)blockIdx.x * blockDim.x + threadIdx.x; idx < total; idx += stride) {
        int h = (int)(idx % H);
        long r = idx / H;
        int t = (int)(r % n_out);
        int jb = (int)(r / n_out);
        int j = jb >> 3;
        int b = jb & 7;
        const float* src = in + j * j_stride + b * b_stride + h;
        int s0 = 2 * t - 6;
        float aL = 0.f, aH = 0.f;
#pragma unroll
        for (int k = 0; k < 8; ++k) {
            int s = s0 + k;
            if (s >= 0 && s < n_in) {
                float v = src[s * t_stride];
                aL += v * h0r[k];
                aH += v * h1r[k];
            }
        }
        long o = ((long)jb * n_out + t) * H + h;
        lo[o] = aL;
        hi[o] = aH;
    }
}

// ---------------- Inverse DWT ----------------
__device__ __forceinline__ float synth_val(const float* lop, const float* hip_, int t)
{
    const float g0[8] = { -0.010597401785069032f, 0.0328830116668852f, 0.030841381835560764f,
                          -0.18703481171909309f, -0.027983769416859854f, 0.6308807679298589f,
                           0.7148465705529157f, 0.2303778133088965f };
    const float g1[8] = { -0.2303778133088965f, 0.7148465705529157f, -0.6308807679298589f,
                          -0.027983769416859854f, 0.18703481171909309f, 0.030841381835560764f,
                          -0.0328830116668852f, -0.010597401785069032f };
    float acc = 0.f;
    if ((t & 1) == 0) {
        int i0 = t >> 1;
#pragma unroll
        for (int d = 0; d < 4; ++d) {
            long i = i0 + d;
            acc += lop[i * H] * g0[2 * d + 1] + hip_[i * H] * g1[2 * d + 1];
        }
    } else {
        int i0 = (t - 1) >> 1;
#pragma unroll
        for (int d = 0; d < 4; ++d) {
            long i = i0 + d;
            acc += lop[i * H] * g0[2 * d] + hip_[i * H] * g1[2 * d];
        }
    }
    return acc;
}

__global__ __launch_bounds__(256)
void dwt_synth_kernel(const float* __restrict__ lo,
                      const float* __restrict__ hi,
                      float* __restrict__ out,
                      int n, int lo_alloc, int n_out)
{
    long total = 24L * n_out * H;
    long stride = (long)gridDim.x * blockDim.x;
    for (long idx = (long)blockIdx.x * blockDim.x + threadIdx.x; idx < total; idx += stride) {
        int h = (int)(idx % H);
        long r = idx / H;
        int t = (int)(r % n_out);
        int mb = (int)(r / n_out);
        const float* lop = lo + (long)mb * lo_alloc * H + h;
        const float* hip_ = hi + (long)mb * n * H + h;
        out[((long)mb * n_out + t) * H + h] = synth_val(lop, hip_, t);
    }
}

__global__ __launch_bounds__(256)
void dwt_synth_final_kernel(const float* __restrict__ lo,
                            const float* __restrict__ hi,
                            const float* __restrict__ x,
                            const float* __restrict__ weight,
                            float* __restrict__ out,
                            int n, int lo_alloc)
{
    long total = 24L * SLEN * H;
    long stride = (long)gridDim.x * blockDim.x;
    for (long idx = (long)blockIdx.x * blockDim.x + threadIdx.x; idx < total; idx += stride) {
        int h = (int)(idx % H);
        long r = idx / H;
        int t = (int)(r % SLEN);
        int mb = (int)(r / SLEN);
        int m = mb >> 3;
        int b = mb & 7;
        const float* lop = lo + (long)mb * lo_alloc * H + h;
        const float* hip_ = hi + (long)mb * n * H + h;
        float recon = synth_val(lop, hip_, t);
        float xs = x[((long)b * SLEN + t) * (3 * H) + (long)m * H + h];
        out[((long)mb * SLEN + t) * H + h] = (recon - xs) * weight[m];
    }
}

// ---------------- bf16 conversion ----------------
// coeff fp32 [3][rows][H] -> bf16 [3][rows_pad][H] (zero-pad rows)
__global__ __launch_bounds__(256)
void cvt_coeff_bf16_kernel(const float* __restrict__ in,
                           unsigned short* __restrict__ out,
                           int rows, int rows_pad)
{
    long total8 = 3L * rows_pad * H / 8;
    long stride = (long)gridDim.x * blockDim.x;
    for (long idx = (long)blockIdx.x * blockDim.x + threadIdx.x; idx < total8; idx += stride) {
        long e = idx * 8;
        int h = (int)(e % H);
        long rr = e / H;
        int r = (int)(rr % rows_pad);
        int j = (int)(rr / rows_pad);
        ushortx8 o;
        if (r < rows) {
            const float* p = in + ((long)j * rows + r) * H + h;
            float4 a = *(const float4*)p;
            float4 b = *(const float4*)(p + 4);
            o[0] = f2bf(a.x); o[1] = f2bf(a.y); o[2] = f2bf(a.z); o[3] = f2bf(a.w);
            o[4] = f2bf(b.x); o[5] = f2bf(b.y); o[6] = f2bf(b.z); o[7] = f2bf(b.w);
        } else {
            o = (ushortx8)0;
        }
        *(ushortx8*)(out + e) = o;
    }
}

__global__ __launch_bounds__(256)
void cvt_flat_bf16_kernel(const float* __restrict__ in,
                          unsigned short* __restrict__ out,
                          long total8)
{
    long stride = (long)gridDim.x * blockDim.x;
    for (long idx = (long)blockIdx.x * blockDim.x + threadIdx.x; idx < total8; idx += stride) {
        long e = idx * 8;
        float4 a = *(const float4*)(in + e);
        float4 b = *(const float4*)(in + e + 4);
        ushortx8 o;
        o[0] = f2bf(a.x); o[1] = f2bf(a.y); o[2] = f2bf(a.z); o[3] = f2bf(a.w);
        o[4] = f2bf(b.x); o[5] = f2bf(b.y); o[6] = f2bf(b.z); o[7] = f2bf(b.w);
        *(ushortx8*)(out + e) = o;
    }
}

// ---------------- Gating via MFMA ----------------
// fused[m,r,g] = sum_j sigmoid( sum_h Abf[j,r,h]*Wbf[m,j,g,h] ) * Abf[j,r,g]
// 128x128 tile, 4 waves (2x2), each wave 64x64 via 4x4 frags of 16x16x32.
__global__ __launch_bounds__(256)
void gating_mfma_kernel(const unsigned short* __restrict__ Abf,  // [3][rows_pad][H]
                        const unsigned short* __restrict__ Wbf,  // strided
                        float* __restrict__ fused,               // [3m][rows][H]
                        int rows, int rows_pad,
                        long w_m_stride, long w_j_stride)
{
    __shared__ unsigned short ldsA[128 * 32];
    __shared__ unsigned short ldsB[128 * 32];
    const int tid = threadIdx.x;
    const int lane = tid & 63;
    const int wid = tid >> 6;
    const int wr = wid >> 1, wc = wid & 1;
    const int m = blockIdx.z;
    const int rowBase = blockIdx.x * 128;
    const int colBase = blockIdx.y * 128;
    const int kq = lane >> 4;     // 0..3
    const int lr = lane & 15;

    f32x4 fus[4][4];
#pragma unroll
    for (int a = 0; a < 4; ++a)
#pragma unroll
        for (int b = 0; b < 4; ++b) fus[a][b] = (f32x4)0.f;

    for (int j = 0; j < 3; ++j) {
        const unsigned short* A  = Abf + (long)j * rows_pad * H;
        const unsigned short* Bw = Wbf + (long)m * w_m_stride + (long)j * w_j_stride;
        f32x4 acc[4][4];
#pragma unroll
        for (int a = 0; a < 4; ++a)
#pragma unroll
            for (int b = 0; b < 4; ++b) acc[a][b] = (f32x4)0.f;

        for (int k0 = 0; k0 < H; k0 += 32) {
            __syncthreads();   // previous iter's LDS reads done
#pragma unroll
            for (int i = 0; i < 2; ++i) {
                const int byteOff = (i * 4 + wid) << 10;   // wave-uniform
                const int e = (byteOff >> 1) + lane * 8;   // element in [128][32] tile
                const unsigned short* ga = A  + (long)(rowBase + (e >> 5)) * H + k0 + (e & 31);
                const unsigned short* gb = Bw + (long)(colBase + (e >> 5)) * H + k0 + (e & 31);
                gload_lds16(ga, (char*)ldsA + byteOff);
                gload_lds16(gb, (char*)ldsB + byteOff);
            }
            __syncthreads();   // compiler drains vmcnt before barrier

            bf16x8 af[4], bfr[4];
#pragma unroll
            for (int mi = 0; mi < 4; ++mi) {
                int r = wr * 64 + mi * 16 + lr;
                af[mi] = *(const bf16x8*)&ldsA[r * 32 + kq * 8];
            }
#pragma unroll
            for (int ni = 0; ni < 4; ++ni) {
                int c = wc * 64 + ni * 16 + lr;
                bfr[ni] = *(const bf16x8*)&ldsB[c * 32 + kq * 8];
            }
#pragma unroll
            for (int mi = 0; mi < 4; ++mi)
#pragma unroll
                for (int ni = 0; ni < 4; ++ni)
                    acc[mi][ni] = __builtin_amdgcn_mfma_f32_16x16x32_bf16(
                        af[mi], bfr[ni], acc[mi][ni], 0, 0, 0);
        }

        // sigmoid-gate epilogue for this j (C/D layout: col=lane&15, row=(lane>>4)*4+reg)
#pragma unroll
        for (int mi = 0; mi < 4; ++mi)
#pragma unroll
            for (int ni = 0; ni < 4; ++ni)
#pragma unroll
                for (int reg = 0; reg < 4; ++reg) {
                    int rl = wr * 64 + mi * 16 + kq * 4 + reg;
                    int gl = wc * 64 + ni * 16 + lr;
                    float c = bf2f(A[(long)(rowBase + rl) * H + colBase + gl]);
                    fus[mi][ni][reg] += sigmoidf(acc[mi][ni][reg]) * c;
                }
    }

#pragma unroll
    for (int mi = 0; mi < 4; ++mi)
#pragma unroll
        for (int ni = 0; ni < 4; ++ni)
#pragma unroll
            for (int reg = 0; reg < 4; ++reg) {
                int r = rowBase + wr * 64 + mi * 16 + kq * 4 + reg;
                if (r < rows) {
                    int g = colBase + wc * 64 + ni * 16 + lr;
                    fused[((long)m * rows + r) * H + g] = fus[mi][ni][reg];
                }
            }
}

// ---------------- launch ----------------
static inline int grid_for(long total) {
    long g = (total + 255) / 256;
    if (g > 16384) g = 16384;
    return (int)g;
}

extern "C" void kernel_launch(void* const* d_in, const int* in_sizes, int n_in,
                              void* d_out, int out_size, void* d_ws, size_t ws_size,
                              hipStream_t stream)
{
    const float* x      = (const float*)d_in[0];
    const float* low_w  = (const float*)d_in[1];
    const float* high_w = (const float*)d_in[2];
    const float* weight = (const float*)d_in[3];
    float* out = (float*)d_out;
    float* ws  = (float*)d_ws;

    const long SZ1 = 24L * N1 * H;
    const long SZ2 = 24L * N2 * H;
    const long SZ3 = 24L * N3 * H;
    const long SZ4 = 24L * N4 * H;
    const long SZA = SZ1 + SZ2 + SZ3 + 2 * SZ4;
    const long HH = (long)H * H;

    // rows (real) and rows_pad (multiple of 128) per band
    const int rows1 = NB * N1, rows1p = 8320;
    const int rows2 = NB * N2, rows2p = 4224;
    const int rows3 = NB * N3, rows3p = 2176;
    const int rows4 = NB * N4, rows4p = 1152;

    // Region A: fp32 forward coeffs; later overwritten by fused outputs
    float* A_hi1 = ws;
    float* A_hi2 = A_hi1 + SZ1;
    float* A_hi3 = A_hi2 + SZ2;
    float* A_hi4 = A_hi3 + SZ3;
    float* A_lo4 = A_hi4 + SZ4;
    float* F_hi1 = A_hi1;  // fused aliases (fp32 coeffs dead after bf16 conversion)
    float* F_hi2 = A_hi2;
    float* F_hi3 = A_hi3;
    float* F_hi4 = A_hi4;
    float* F_lo  = A_lo4;

    // Region C: forward lo intermediates -> bf16 arrays -> synthesis intermediates
    float* RC    = ws + SZA;
    float* B_lo1 = RC;
    float* B_lo2 = RC + SZ1;
    float* B_lo3 = B_lo2 + SZ2;

    unsigned short* Abf1 = (unsigned short*)RC;
    unsigned short* Abf2 = Abf1 + 3L * rows1p * H;
    unsigned short* Abf3 = Abf2 + 3L * rows2p * H;
    unsigned short* Abf4 = Abf3 + 3L * rows3p * H;
    unsigned short* AbfL = Abf4 + 3L * rows4p * H;
    unsigned short* Wl_bf = AbfL + 3L * rows4p * H;
    unsigned short* Wh_bf = Wl_bf + 9L * HH;

    float* Y1 = RC;
    float* Y2 = Y1 + 24L * 262 * H;
    float* Y3 = Y2 + 24L * 518 * H;

    // ---- forward DWT ----
    hipLaunchKernelGGL(dwt_analysis_kernel, dim3(grid_for(24L * N1 * H)), dim3(256), 0, stream,
                       x, B_lo1, A_hi1, SLEN, N1, 768L, (long)SLEN * 2304, 2304L);
    hipLaunchKernelGGL(dwt_analysis_kernel, dim3(grid_for(24L * N2 * H)), dim3(256), 0, stream,
                       B_lo1, B_lo2, A_hi2, N1, N2, 8L * N1 * H, (long)N1 * H, (long)H);
    hipLaunchKernelGGL(dwt_analysis_kernel, dim3(grid_for(24L * N3 * H)), dim3(256), 0, stream,
                       B_lo2, B_lo3, A_hi3, N2, N3, 8L * N2 * H, (long)N2 * H, (long)H);
    hipLaunchKernelGGL(dwt_analysis_kernel, dim3(grid_for(24L * N4 * H)), dim3(256), 0, stream,
                       B_lo3, A_lo4, A_hi4, N3, N4, 8L * N3 * H, (long)N3 * H, (long)H);

    // ---- bf16 conversions (lo intermediates now dead) ----
    hipLaunchKernelGGL(cvt_coeff_bf16_kernel, dim3(grid_for(3L * rows1p * H / 8)), dim3(256), 0, stream,
                       A_hi1, Abf1, rows1, rows1p);
    hipLaunchKernelGGL(cvt_coeff_bf16_kernel, dim3(grid_for(3L * rows2p * H / 8)), dim3(256), 0, stream,
                       A_hi2, Abf2, rows2, rows2p);
    hipLaunchKernelGGL(cvt_coeff_bf16_kernel, dim3(grid_for(3L * rows3p * H / 8)), dim3(256), 0, stream,
                       A_hi3, Abf3, rows3, rows3p);
    hipLaunchKernelGGL(cvt_coeff_bf16_kernel, dim3(grid_for(3L * rows4p * H / 8)), dim3(256), 0, stream,
                       A_hi4, Abf4, rows4, rows4p);
    hipLaunchKernelGGL(cvt_coeff_bf16_kernel, dim3(grid_for(3L * rows4p * H / 8)), dim3(256), 0, stream,
                       A_lo4, AbfL, rows4, rows4p);
    hipLaunchKernelGGL(cvt_flat_bf16_kernel, dim3(grid_for(9L * HH / 8)), dim3(256), 0, stream,
                       low_w, Wl_bf, 9L * HH / 8);
    hipLaunchKernelGGL(cvt_flat_bf16_kernel, dim3(grid_for(36L * HH / 8)), dim3(256), 0, stream,
                       high_w, Wh_bf, 36L * HH / 8);

    // ---- gating (MFMA) ----
    hipLaunchKernelGGL(gating_mfma_kernel, dim3(rows4p / 128, H / 128, 3), dim3(256), 0, stream,
                       AbfL, Wl_bf, F_lo, rows4, rows4p, 3L * HH, HH);
    hipLaunchKernelGGL(gating_mfma_kernel, dim3(rows1p / 128, H / 128, 3), dim3(256), 0, stream,
                       Abf1, Wh_bf + 0L * 3 * HH, F_hi1, rows1, rows1p, 12L * HH, HH);
    hipLaunchKernelGGL(gating_mfma_kernel, dim3(rows2p / 128, H / 128, 3), dim3(256), 0, stream,
                       Abf2, Wh_bf + 1L * 3 * HH, F_hi2, rows2, rows2p, 12L * HH, HH);
    hipLaunchKernelGGL(gating_mfma_kernel, dim3(rows3p / 128, H / 128, 3), dim3(256), 0, stream,
                       Abf3, Wh_bf + 2L * 3 * HH, F_hi3, rows3, rows3p, 12L * HH, HH);
    hipLaunchKernelGGL(gating_mfma_kernel, dim3(rows4p / 128, H / 128, 3), dim3(256), 0, stream,
                       Abf4, Wh_bf + 3L * 3 * HH, F_hi4, rows4, rows4p, 12L * HH, HH);

    // ---- inverse DWT (bf16 arrays dead; Y aliases them) ----
    hipLaunchKernelGGL(dwt_synth_kernel, dim3(grid_for(24L * 262 * H)), dim3(256), 0, stream,
                       F_lo, F_hi4, Y1, N4, N4, 2 * N4 - 6);
    hipLaunchKernelGGL(dwt_synth_kernel, dim3(grid_for(24L * 518 * H)), dim3(256), 0, stream,
                       Y1, F_hi3, Y2, N3, N3, 2 * N3 - 6);
    hipLaunchKernelGGL(dwt_synth_kernel, dim3(grid_for(24L * 1028 * H)), dim3(256), 0, stream,
                       Y2, F_hi2, Y3, N2, 518, 2 * N2 - 6);
    hipLaunchKernelGGL(dwt_synth_final_kernel, dim3(grid_for(24L * SLEN * H)), dim3(256), 0, stream,
                       Y3, F_hi1, x, weight, out, N1, 1028);
}